// Round 1
// baseline (1122.790 us; speedup 1.0000x reference)
//
#include <hip/hip_runtime.h>

#define BB 64
#define TT 2048
#define DD 512
#define UU 32

// ---------------------------------------------------------------------------
// K1: logits[b,t,u] = sum_k x[b,t,k]*kernel[k,u] + bias[u]
// grid 512 x 256 threads. BM=256 rows/block, BK=32.
// LDS: xs [256][34] (row-major, pitch 34 breaks conflicts, float2-alignable),
//      wsh [32][36] (pitch 36 keeps float4 alignment for u-quads).
// thread micro-tile: 4 rows (tr + 64*i) x 8 contiguous u (tc*8..tc*8+7).
// ---------------------------------------------------------------------------
__global__ __launch_bounds__(256) void k1_logits(const float* __restrict__ x,
                                                 const float* __restrict__ w,
                                                 const float* __restrict__ bias,
                                                 float* __restrict__ out) {
  __shared__ float xs[256 * 34];
  __shared__ float wsh[32 * 36];
  const int tid = threadIdx.x;
  const long row0 = (long)blockIdx.x * 256;
  const int tr = tid >> 2;         // 0..63
  const int tc = tid & 3;          // 0..3
  const int ubase = tc * 8;
  const int sr = tid >> 3;         // staging row within pass (0..31)
  const int sc = (tid & 7) * 4;    // staging col (0,4,..,28)

  float acc[4][8];
#pragma unroll
  for (int i = 0; i < 4; ++i)
#pragma unroll
    for (int j = 0; j < 8; ++j) acc[i][j] = 0.0f;

  for (int kc = 0; kc < DD; kc += 32) {
    // stage x tile: 256 rows x 32 k
#pragma unroll
    for (int p = 0; p < 8; ++p) {
      const int r = p * 32 + sr;
      const float4 v = *(const float4*)(x + (row0 + r) * DD + kc + sc);
      *(float2*)(&xs[r * 34 + sc]) = make_float2(v.x, v.y);
      *(float2*)(&xs[r * 34 + sc + 2]) = make_float2(v.z, v.w);
    }
    // stage w tile: 32 k x 32 u
    {
      const int k = tid >> 3;
      const int uu4 = (tid & 7) * 4;
      const float4 v = *(const float4*)(w + (size_t)(kc + k) * UU + uu4);
      *(float4*)(&wsh[k * 36 + uu4]) = v;
    }
    __syncthreads();
#pragma unroll
    for (int k = 0; k < 32; ++k) {
      const float4 w0 = *(const float4*)(&wsh[k * 36 + ubase]);
      const float4 w1 = *(const float4*)(&wsh[k * 36 + ubase + 4]);
      const float wv[8] = {w0.x, w0.y, w0.z, w0.w, w1.x, w1.y, w1.z, w1.w};
#pragma unroll
      for (int i = 0; i < 4; ++i) {
        const float xv = xs[(tr + 64 * i) * 34 + k];
#pragma unroll
        for (int j = 0; j < 8; ++j) acc[i][j] = fmaf(xv, wv[j], acc[i][j]);
      }
    }
    __syncthreads();
  }
  float bv[8];
#pragma unroll
  for (int j = 0; j < 8; ++j) bv[j] = bias[ubase + j];
#pragma unroll
  for (int i = 0; i < 4; ++i) {
    const long row = row0 + tr + 64 * i;
    float4 o0, o1;
    o0.x = acc[i][0] + bv[0]; o0.y = acc[i][1] + bv[1];
    o0.z = acc[i][2] + bv[2]; o0.w = acc[i][3] + bv[3];
    o1.x = acc[i][4] + bv[4]; o1.y = acc[i][5] + bv[5];
    o1.z = acc[i][6] + bv[6]; o1.w = acc[i][7] + bv[7];
    *(float4*)(out + row * UU + ubase) = o0;
    *(float4*)(out + row * UU + ubase + 4) = o1;
  }
}

// ---------------------------------------------------------------------------
// K2: Viterbi forward. One wave per chain. lane = h*32+u; lane (u,h) reduces
// over v in [16h,16h+16) with trans column cached in regs; alpha[v] broadcast
// via ds_bpermute; halves combined with shfl_xor(32). alpha_t overwrites the
// logits row in place (rows < nwords become alpha rows; later rows unused).
// Also emits best_score[b] = max_u alpha_{nw-1}[u].
// ---------------------------------------------------------------------------
__global__ __launch_bounds__(64) void k2_forward(float* __restrict__ lb,
                                                 const float* __restrict__ trans,
                                                 const int* __restrict__ nwords,
                                                 float* __restrict__ score) {
  const int b = blockIdx.x;
  const int lane = threadIdx.x;
  const int u = lane & 31;
  const int h = lane >> 5;

  float tv[16];
#pragma unroll
  for (int i = 0; i < 16; ++i) tv[i] = trans[(h * 16 + i) * UU + u];

  float* base = lb + (size_t)b * TT * UU;
  float alpha = base[u];  // row 0 = alpha0 (bias already added in K1)
  const int nw = nwords[b];
  const int nwm1 = nw - 1;

  // depth-2 logits prefetch (rows always physically in-bounds; clamped reads unused)
  float lg0 = base[1 * UU + u];
  float lg1 = base[2 * UU + u];

  for (int t = 1; t < nw; ++t) {
    int tpre = t + 2;
    if (tpre > nwm1) tpre = (nwm1 > 1) ? nwm1 : 1;
    const float lgN = base[(size_t)tpre * UU + u];

    float m0 = -3.4e38f, m1 = -3.4e38f;
#pragma unroll
    for (int i = 0; i < 16; ++i) {
      const int av =
          __builtin_amdgcn_ds_bpermute((h * 16 + i) << 2, __float_as_int(alpha));
      const float c = __int_as_float(av) + tv[i];
      if (i & 1) m1 = fmaxf(m1, c); else m0 = fmaxf(m0, c);
    }
    float mh = fmaxf(m0, m1);
    const float mo = __shfl_xor(mh, 32);
    alpha = fmaxf(mh, mo) + lg0;
    if (h == 0) base[(size_t)t * UU + u] = alpha;
    lg0 = lg1;
    lg1 = lgN;
  }
  float m = alpha;
#pragma unroll
  for (int s = 32; s; s >>= 1) m = fmaxf(m, __shfl_xor(m, s));
  if (lane == 0) score[b] = m;  // stored as f32 bits (see dtype bet)
}

// ---------------------------------------------------------------------------
// K3: backpointers, fully parallel from stored alpha rows.
// bp[b][u][t] (transposed, bytes) for t in [1,2047]: argmax_v(alpha[t-1][v]+trans[v][u]),
// first-index tie-break; identity (u) for t >= nwords. t=0 slot is dummy.
// grid: 64*16 blocks x 256 thr; block covers t in [128c, 128c+128).
// ---------------------------------------------------------------------------
__global__ __launch_bounds__(256) void k3_bp(const float* __restrict__ lb,
                                             const float* __restrict__ trans,
                                             const int* __restrict__ nwords,
                                             unsigned char* __restrict__ bp) {
  __shared__ float as[129 * 32];
  __shared__ float ts[32 * 32];
  const int b = blockIdx.x >> 4;
  const int c = blockIdx.x & 15;
  const int t0 = 128 * c;
  const int tid = threadIdx.x;
  const float* base = lb + (size_t)b * TT * UU;
  const int nw = nwords[b];

  for (int idx = tid; idx < 129 * 32; idx += 256) {
    const int gidx = (t0 - 1) * 32 + idx;  // row t0-1+.. ; c=0 row -1 is dummy
    as[idx] = (gidx >= 0 && gidx < TT * UU) ? base[gidx] : 0.0f;
  }
  for (int idx = tid; idx < 1024; idx += 256) ts[idx] = trans[idx];
  __syncthreads();

  const int u = tid & 31;
  const int tg = tid >> 5;  // 0..7
  unsigned char* bpu = bp + ((size_t)b * 32 + u) * TT;

#pragma unroll 1
  for (int q = 0; q < 4; ++q) {
    const int tl0 = tg * 16 + q * 4;
    unsigned int pack = 0;
#pragma unroll
    for (int e = 0; e < 4; ++e) {
      const int tl = tl0 + e;
      const int t = t0 + tl;
      int idx;
      if (t >= 1 && t < nw) {
        float m = as[tl * 32 + 0] + ts[0 * 32 + u];
        idx = 0;
#pragma unroll
        for (int v = 1; v < 32; ++v) {
          const float cv = as[tl * 32 + v] + ts[v * 32 + u];
          if (cv > m) { m = cv; idx = v; }
        }
      } else {
        idx = u;  // identity step (and dummy for t=0)
      }
      pack |= ((unsigned int)idx) << (8 * e);
    }
    *(unsigned int*)(bpu + t0 + tl0) = pack;
  }
}

// ---------------------------------------------------------------------------
// K4: backtrace. One wave per chain. last_tag = first-argmax of alpha[nw-1].
// pred[t]=last_tag for t>=nw-1 (bulk). Then chase t=nw-1..1 with bp held in
// VGPRs (64 t's = 16 dwords per u, spread as w[8] over lanes (u,h)); tag kept
// wave-uniform, extracted with v_readlane. pred stored as raw int32.
// ---------------------------------------------------------------------------
__global__ __launch_bounds__(64) void k4_backtrace(const float* __restrict__ lb,
                                                   const unsigned char* __restrict__ bp,
                                                   const int* __restrict__ nwords,
                                                   int* __restrict__ pred) {
  const int b = blockIdx.x;
  const int lane = threadIdx.x;
  const int u = lane & 31;
  const int h = lane >> 5;
  const int nw = nwords[b];

  const float a = lb[((size_t)b * TT + (nw - 1)) * UU + u];
  float m = a;
#pragma unroll
  for (int s = 32; s; s >>= 1) m = fmaxf(m, __shfl_xor(m, s));
  const unsigned long long mask = __ballot(lane < 32 && a == m);
  int tag = __ffsll((unsigned long long)mask) - 1;
  tag = __builtin_amdgcn_readfirstlane(tag);

  int* predb = pred + b * TT;
  for (int p = nw - 1 + lane; p < TT; p += 64) predb[p] = tag;
  if (nw < 2) return;

  const unsigned char* bpb = bp + (size_t)b * 32 * TT;
  const int pcmax = (nw - 2) >> 6;
  const int thi_top = nw - 1;

  int wprev0 = 0;
  {
    const int toff = (pcmax + 1) * 64;
    if (toff < TT) wprev0 = *(const int*)(bpb + (size_t)u * TT + toff);
  }

  for (int pc = pcmax; pc >= 0; --pc) {
    int wreg[8];
#pragma unroll
    for (int j = 0; j < 8; ++j)
      wreg[j] = *(const int*)(bpb + (size_t)u * TT + pc * 64 + 4 * (h * 8 + j));
    const int thi = (pc == pcmax) ? thi_top : (pc * 64 + 64);
    int predv = 0;

    if (pc * 64 + 64 <= thi) {  // step t = pc*64+64 uses prev chunk's dword 0
      const int val = __builtin_amdgcn_readlane(wprev0, tag);
      tag = __builtin_amdgcn_readfirstlane(val & 0xFF);
      if (lane == 63) predv = tag;
    }
#pragma unroll
    for (int lt = 63; lt >= 1; --lt) {
      if (pc * 64 + lt <= thi) {
        const int d = lt >> 2, byte = lt & 3;
        const int hs = d >> 3, j = d & 7;
        const int val = __builtin_amdgcn_readlane(wreg[j], hs * 32 + tag);
        tag = __builtin_amdgcn_readfirstlane((val >> (8 * byte)) & 0xFF);
        if (lane == lt - 1) predv = tag;
      }
    }
    const int lim = thi - pc * 64;  // outputs p = pc*64 + lane, lane < lim
    if (lane < lim) predb[pc * 64 + lane] = predv;
    wprev0 = wreg[0];
  }
}

// ---------------------------------------------------------------------------
extern "C" void kernel_launch(void* const* d_in, const int* in_sizes, int n_in,
                              void* d_out, int out_size, void* d_ws, size_t ws_size,
                              hipStream_t stream) {
  const float* x = (const float*)d_in[0];
  const int* nwords = (const int*)d_in[1];
  const float* kern = (const float*)d_in[2];
  const float* chain = (const float*)d_in[3];
  const float* bias = (const float*)d_in[4];

  float* logits = (float*)d_ws;                                   // 16 MB
  unsigned char* bp = (unsigned char*)d_ws + (size_t)BB * TT * UU * 4;  // +4 MB

  int* pred = (int*)d_out;                       // [B,T] raw int32 tags
  float* score = (float*)d_out + (size_t)BB * TT;  // [B] f32

  k1_logits<<<dim3(512), dim3(256), 0, stream>>>(x, kern, bias, logits);
  k2_forward<<<dim3(BB), dim3(64), 0, stream>>>(logits, chain, nwords, score);
  k3_bp<<<dim3(BB * 16), dim3(256), 0, stream>>>(logits, chain, nwords, bp);
  k4_backtrace<<<dim3(BB), dim3(64), 0, stream>>>(logits, bp, nwords, pred);
}